// Round 3
// baseline (387.218 us; speedup 1.0000x reference)
//
#include <hip/hip_runtime.h>
#include <hip/hip_bf16.h>

#define BB 16
#define LL 4096
#define PDIM 512
#define HH 256
#define HALFD 128
#define TP 16

// ---------------- Kernel A: W [256,512] -> Wt [512,256] ----------------
__global__ __launch_bounds__(256) void wt_kernel(const float* __restrict__ W,
                                                 float* __restrict__ Wt) {
  int idx = blockIdx.x * 256 + threadIdx.x;  // 0..131071, coalesced read
  int h = idx >> 9;
  int k = idx & 511;
  Wt[k * HH + h] = W[idx];
}

// ---------------- Kernel B: fs embedding MLP -> fs_emb [16,256] ----------------
__global__ __launch_bounds__(256) void fsemb_kernel(
    const float* __restrict__ fs, const float* __restrict__ w1,
    const float* __restrict__ b1, const float* __restrict__ w2,
    const float* __restrict__ b2, float* __restrict__ fs_emb) {
  int b = blockIdx.x, h = threadIdx.x;
  __shared__ float tf[HH];
  __shared__ float hid[HH];
  float fv = fs[b];
  int i = h & (HALFD - 1);
  float freq = expf(-9.210340371976184f * (float)i / 128.0f);
  float arg = fv * freq;
  tf[h] = (h < HALFD) ? cosf(arg) : sinf(arg);
  __syncthreads();
  float acc = b1[h];
  const float* wr = w1 + (size_t)h * HH;
  for (int k = 0; k < HH; k += 4) {
    float4 w4 = *reinterpret_cast<const float4*>(&wr[k]);
    acc += tf[k] * w4.x + tf[k + 1] * w4.y + tf[k + 2] * w4.z + tf[k + 3] * w4.w;
  }
  hid[h] = acc / (1.0f + expf(-acc));  // silu
  __syncthreads();
  float acc2 = b2[h];
  const float* wr2 = w2 + (size_t)h * HH;
  for (int k = 0; k < HH; k += 4) {
    float4 w4 = *reinterpret_cast<const float4*>(&wr2[k]);
    acc2 += hid[k] * w4.x + hid[k + 1] * w4.y + hid[k + 2] * w4.z + hid[k + 3] * w4.w;
  }
  fs_emb[b * HH + h] = acc2;
}

// ---------------- Kernel C: per-row stable sort + index outputs (fp32 out) ----------------
__global__ __launch_bounds__(1024) void sort_kernel(
    const int* __restrict__ sample_ids, const int* __restrict__ eff_lens,
    const float* __restrict__ noise, float* __restrict__ out_mae,
    float* __restrict__ out_restore, float* __restrict__ out_unmask,
    int* __restrict__ keep_idx, int* __restrict__ lk_arr) {
  const int b = blockIdx.x, tid = threadIdx.x;
  __shared__ unsigned long long keys[LL];   // (value_bits<<32)|index
  __shared__ int rank1[LL];
  __shared__ int sc[2][1024];
  const int eff = eff_lens[b];
  const int* sid = sample_ids + (size_t)b * LL;
  const float* nrow = noise + (size_t)b * LL;

  int local_ns = 0;
  for (int j = tid; j < LL; j += 1024) {
    int s = sid[j];
    int sp = (j >= 1) ? sid[j - 1] : -1;
    int spp = (j >= 2) ? sid[j - 2] : -1;
    bool valid = j < eff;
    bool segs = valid && (s != sp);
    bool fst = valid && (j > 0) && (sp != spp);
    local_ns += segs ? 1 : 0;
    unsigned vb;
    if (!valid) vb = 0x7F800000u;            // +inf
    else if (segs || fst) vb = 0u;           // 0.0f
    else vb = __float_as_uint(nrow[j]);      // noise in [0,1): bits monotone
    keys[j] = (((unsigned long long)vb) << 32) | (unsigned)j;
  }
  // reduce num_samples
  sc[0][tid] = local_ns;
  __syncthreads();
  for (int off = 512; off > 0; off >>= 1) {
    if (tid < off) sc[0][tid] += sc[0][tid + off];
    __syncthreads();
  }
  const int ns = sc[0][0];
  const int lk = 2 * ns + ((eff - 2 * ns) >> 2);  // exact integer arithmetic
  __syncthreads();

  // bitonic sort ascending, 4096 u64 keys (distinct keys -> equals stable sort)
  for (int k = 2; k <= LL; k <<= 1) {
    for (int js = k >> 1; js > 0; js >>= 1) {
      for (int i = tid; i < LL; i += 1024) {
        int ixj = i ^ js;
        if (ixj > i) {
          unsigned long long a = keys[i], c = keys[ixj];
          bool ascdir = (i & k) == 0;
          if ((a > c) == ascdir) { keys[i] = c; keys[ixj] = a; }
        }
      }
      __syncthreads();
    }
  }
  // rank of each original index
  for (int p = tid; p < LL; p += 1024)
    rank1[(int)(keys[p] & 0xFFFFFFFFull)] = p;
  __syncthreads();

  // exclusive prefix sum over kept flags (index order)
  const int base = tid * 4;
  int c4[4]; int cnt = 0;
  for (int q = 0; q < 4; ++q) { c4[q] = (rank1[base + q] < lk) ? 1 : 0; cnt += c4[q]; }
  int cur = 0;
  sc[0][tid] = cnt;
  __syncthreads();
  for (int off = 1; off < 1024; off <<= 1) {
    int v = sc[cur][tid];
    if (tid >= off) v += sc[cur][tid - off];
    sc[cur ^ 1][tid] = v;
    __syncthreads();
    cur ^= 1;
  }
  int run = sc[cur][tid] - cnt;  // exclusive prefix

  float4 rst, mmk;
  float* rp = &rst.x; float* mp = &mmk.x;
  for (int q = 0; q < 4; ++q) {
    int j = base + q;
    int r;
    if (c4[q]) {
      r = run;
      keep_idx[b * LL + run] = j;                          // global scatter
      out_unmask[(size_t)b * LL + run] = (float)sid[j];    // kept slot
      run++;
    } else {
      r = rank1[j];
    }
    rp[q] = (float)r;
    mp[q] = (r >= lk && r < eff) ? 1.0f : 0.0f;
  }
  *reinterpret_cast<float4*>(out_restore + (size_t)b * LL + base) = rst;
  *reinterpret_cast<float4*>(out_mae + (size_t)b * LL + base) = mmk;

  // positions beyond len_keep: unmask_ids = -1 (disjoint from kept-slot writes)
  for (int p = tid; p < LL; p += 1024)
    if (p >= lk) out_unmask[(size_t)b * LL + p] = -1.0f;
  if (tid == 0) lk_arr[b] = lk;
}

// ---------------- Kernel D: gather + projection GEMM + epilogue (fp32 out) ----------------
__global__ __launch_bounds__(256) void proj_kernel(
    const float* __restrict__ patches, const float* __restrict__ Wt,
    const float* __restrict__ bias, const float* __restrict__ pos,
    const float* __restrict__ fs_emb, const int* __restrict__ keep_idx,
    const int* __restrict__ lk_arr, float* __restrict__ out0) {
  const int tile = blockIdx.x, b = blockIdx.y, tid = threadIdx.x;
  const int p0 = tile * TP;
  int lk = lk_arr[b];
  lk = lk < 0 ? 0 : (lk > LL ? LL : lk);   // defensive clamp
  const int h0 = (tid & 63) * 4;
  const int t0 = (tid >> 6) * 4;
  __shared__ __align__(16) float pT[PDIM * 20];  // [k][t], stride 20
  __shared__ int idxs[TP];
  int nt = lk - p0;
  nt = nt > TP ? TP : nt;

  if (nt > 0) {
    if (tid < nt) idxs[tid] = keep_idx[b * LL + p0 + tid] & (LL - 1);  // defensive mask
    __syncthreads();
    for (int t = 0; t < nt; ++t) {
      const float* row = patches + ((size_t)b * LL + (size_t)idxs[t]) * PDIM;
      pT[tid * 20 + t] = row[tid];
      pT[(tid + 256) * 20 + t] = row[tid + 256];
    }
    __syncthreads();
    float acc[4][4] = {};
    for (int k = 0; k < PDIM; ++k) {
      float4 pv = *reinterpret_cast<const float4*>(&pT[k * 20 + t0]);  // LDS broadcast
      float4 wv = *reinterpret_cast<const float4*>(&Wt[(size_t)k * HH + h0]);
      acc[0][0] += pv.x * wv.x; acc[0][1] += pv.x * wv.y; acc[0][2] += pv.x * wv.z; acc[0][3] += pv.x * wv.w;
      acc[1][0] += pv.y * wv.x; acc[1][1] += pv.y * wv.y; acc[1][2] += pv.y * wv.z; acc[1][3] += pv.y * wv.w;
      acc[2][0] += pv.z * wv.x; acc[2][1] += pv.z * wv.y; acc[2][2] += pv.z * wv.z; acc[2][3] += pv.z * wv.w;
      acc[3][0] += pv.w * wv.x; acc[3][1] += pv.w * wv.y; acc[3][2] += pv.w * wv.z; acc[3][3] += pv.w * wv.w;
    }
    float4 bv = *reinterpret_cast<const float4*>(&bias[h0]);
    float4 fe = *reinterpret_cast<const float4*>(&fs_emb[b * HH + h0]);
    for (int i = 0; i < 4; ++i) {
      int p = p0 + t0 + i;
      float* op = out0 + ((size_t)b * LL + p) * HH + h0;
      if (p < lk) {
        int idx = idxs[t0 + i];
        float4 pz = *reinterpret_cast<const float4*>(&pos[(size_t)idx * HH + h0]);
        float4 u;
        u.x = acc[i][0] + bv.x + pz.x + fe.x;
        u.y = acc[i][1] + bv.y + pz.y + fe.y;
        u.z = acc[i][2] + bv.z + pz.z + fe.z;
        u.w = acc[i][3] + bv.w + pz.w + fe.w;
        *reinterpret_cast<float4*>(op) = u;
      } else {
        *reinterpret_cast<float4*>(op) = make_float4(0.f, 0.f, 0.f, 0.f);
      }
    }
  } else {
    for (int i = 0; i < 4; ++i) {
      int p = p0 + t0 + i;
      float* op = out0 + ((size_t)b * LL + p) * HH + h0;
      *reinterpret_cast<float4*>(op) = make_float4(0.f, 0.f, 0.f, 0.f);
    }
  }
}

extern "C" void kernel_launch(void* const* d_in, const int* in_sizes, int n_in,
                              void* d_out, int out_size, void* d_ws, size_t ws_size,
                              hipStream_t stream) {
  const float* patches = (const float*)d_in[0];
  const int* sample_ids = (const int*)d_in[1];
  const int* eff = (const int*)d_in[2];
  const float* noise = (const float*)d_in[3];
  const float* fs = (const float*)d_in[4];
  const float* W = (const float*)d_in[5];
  const float* bias = (const float*)d_in[6];
  const float* pos = (const float*)d_in[7];
  const float* w1 = (const float*)d_in[8];
  const float* b1 = (const float*)d_in[9];
  const float* w2 = (const float*)d_in[10];
  const float* b2 = (const float*)d_in[11];

  float* out0 = (float*)d_out;                            // seq_unmasked fp32 [16,4096,256]
  float* out_mae = out0 + (size_t)BB * LL * HH;           // mae_mask   [16,4096]
  float* out_restore = out_mae + (size_t)BB * LL;         // ids_restore[16,4096]
  float* out_unmask = out_restore + (size_t)BB * LL;      // unmask_ids [16,4096]

  char* ws = (char*)d_ws;
  float* Wt = (float*)ws;                        // 512*256*4 = 524288
  float* fs_emb = (float*)(ws + 524288);         // 16*256*4  = 16384
  int* keep_idx = (int*)(ws + 540672);           // 16*4096*4 = 262144
  int* lk_arr = (int*)(ws + 802816);             // 64
  if (ws_size < 802880) return;

  wt_kernel<<<512, 256, 0, stream>>>(W, Wt);
  fsemb_kernel<<<BB, 256, 0, stream>>>(fs, w1, b1, w2, b2, fs_emb);
  sort_kernel<<<BB, 1024, 0, stream>>>(sample_ids, eff, noise, out_mae,
                                       out_restore, out_unmask, keep_idx, lk_arr);
  proj_kernel<<<dim3(LL / TP, BB), 256, 0, stream>>>(patches, Wt, bias, pos,
                                                     fs_emb, keep_idx, lk_arr, out0);
}

// Round 4
// 358.654 us; speedup vs baseline: 1.0796x; 1.0796x over previous
//
#include <hip/hip_runtime.h>
#include <hip/hip_bf16.h>

#define BB 16
#define LL 4096
#define PDIM 512
#define HH 256
#define HALFD 128
#define TP 16

__device__ __forceinline__ unsigned short f2bf(float f) {
  unsigned x = __float_as_uint(f);
  unsigned r = (x + 0x7FFFu + ((x >> 16) & 1u)) >> 16;
  return (unsigned short)r;
}
__device__ __forceinline__ float bf2f(unsigned short u) {
  return __uint_as_float(((unsigned)u) << 16);
}

// stable-sort key for element j of row b: (value_bits << 32) | j  (unique)
__device__ __forceinline__ unsigned long long make_key(
    const int* __restrict__ sid, const float* __restrict__ nrow, int eff, int j) {
  int s = sid[j];
  int sp = (j >= 1) ? sid[j - 1] : -1;
  int spp = (j >= 2) ? sid[j - 2] : -1;
  bool valid = j < eff;
  bool segs = valid && (s != sp);
  bool fst = valid && (j > 0) && (sp != spp);
  unsigned vb;
  if (!valid) vb = 0x7F800000u;            // +inf
  else if (segs || fst) vb = 0u;           // prefix tokens: noise 0
  else vb = __float_as_uint(nrow[j]);      // noise in [0,1): bits monotone
  return (((unsigned long long)vb) << 32) | (unsigned)j;
}

// ---------------- Kernel A: W [256,512] -> Wt [512,256] ----------------
__global__ __launch_bounds__(256) void wt_kernel(const float* __restrict__ W,
                                                 float* __restrict__ Wt) {
  int idx = blockIdx.x * 256 + threadIdx.x;
  int h = idx >> 9;
  int k = idx & 511;
  Wt[k * HH + h] = W[idx];
}

// ---------------- zero rank_ws ----------------
__global__ __launch_bounds__(256) void zero_kernel(int* __restrict__ rank_ws) {
  rank_ws[blockIdx.x * 256 + threadIdx.x] = 0;
}

// ---------------- Kernel B: fs embedding MLP -> fs_emb [16,256] ----------------
__global__ __launch_bounds__(256) void fsemb_kernel(
    const float* __restrict__ fs, const float* __restrict__ w1,
    const float* __restrict__ b1, const float* __restrict__ w2,
    const float* __restrict__ b2, float* __restrict__ fs_emb) {
  int b = blockIdx.x, h = threadIdx.x;
  __shared__ float tf[HH];
  __shared__ float hid[HH];
  float fv = fs[b];
  int i = h & (HALFD - 1);
  float freq = expf(-9.210340371976184f * (float)i / 128.0f);
  float arg = fv * freq;
  tf[h] = (h < HALFD) ? cosf(arg) : sinf(arg);
  __syncthreads();
  float acc = b1[h];
  const float* wr = w1 + (size_t)h * HH;
  for (int k = 0; k < HH; k += 4) {
    float4 w4 = *reinterpret_cast<const float4*>(&wr[k]);
    acc += tf[k] * w4.x + tf[k + 1] * w4.y + tf[k + 2] * w4.z + tf[k + 3] * w4.w;
  }
  hid[h] = acc / (1.0f + expf(-acc));
  __syncthreads();
  float acc2 = b2[h];
  const float* wr2 = w2 + (size_t)h * HH;
  for (int k = 0; k < HH; k += 4) {
    float4 w4 = *reinterpret_cast<const float4*>(&wr2[k]);
    acc2 += hid[k] * w4.x + hid[k + 1] * w4.y + hid[k + 2] * w4.z + hid[k + 3] * w4.w;
  }
  fs_emb[b * HH + h] = acc2;
}

// ---------------- Kernel C1: counting rank (partial, atomic merge) ----------------
// grid: (4 key-slices, 4 elem-quarters, 16 rows) x 1024 threads.
// rank[e] = #{keys < key[e]} == stable argsort position (keys unique).
__global__ __launch_bounds__(1024) void rank_kernel(
    const int* __restrict__ sample_ids, const int* __restrict__ eff_lens,
    const float* __restrict__ noise, int* __restrict__ rank_ws) {
  const int ks = blockIdx.x, eq = blockIdx.y, b = blockIdx.z, tid = threadIdx.x;
  __shared__ __align__(16) unsigned long long sk[1024];
  const int eff = eff_lens[b];
  const int* sid = sample_ids + (size_t)b * LL;
  const float* nrow = noise + (size_t)b * LL;

  sk[tid] = make_key(sid, nrow, eff, ks * 1024 + tid);
  __syncthreads();

  const int e = eq * 1024 + tid;
  const unsigned long long mykey = make_key(sid, nrow, eff, e);
  int cnt = 0;
#pragma unroll 4
  for (int k = 0; k < 1024; k += 2) {
    ulonglong2 kk = *reinterpret_cast<const ulonglong2*>(&sk[k]);  // broadcast
    cnt += (kk.x < mykey) ? 1 : 0;
    cnt += (kk.y < mykey) ? 1 : 0;
  }
  atomicAdd(&rank_ws[b * LL + e], cnt);
}

// ---------------- Kernel C2: finalize (prefix-scan of kept, all index outputs) ----------------
__global__ __launch_bounds__(1024) void finalize_kernel(
    const int* __restrict__ sample_ids, const int* __restrict__ eff_lens,
    const int* __restrict__ rank_ws, float* __restrict__ out_mae,
    float* __restrict__ out_restore, float* __restrict__ out_unmask,
    int* __restrict__ keep_idx, int* __restrict__ lk_arr) {
  const int b = blockIdx.x, tid = threadIdx.x;
  __shared__ int sc[2][1024];
  const int eff = eff_lens[b];
  const int* sid = sample_ids + (size_t)b * LL;

  // num segment starts -> len_keep
  int local_ns = 0;
  for (int j = tid; j < LL; j += 1024) {
    int s = sid[j];
    int sp = (j >= 1) ? sid[j - 1] : -1;
    if (j < eff && s != sp) local_ns++;
  }
  sc[0][tid] = local_ns;
  __syncthreads();
  for (int off = 512; off > 0; off >>= 1) {
    if (tid < off) sc[0][tid] += sc[0][tid + off];
    __syncthreads();
  }
  const int ns = sc[0][0];
  const int lk = 2 * ns + ((eff - 2 * ns) >> 2);  // exact
  __syncthreads();

  // kept flags + exclusive prefix (index order), 4 elems/thread
  const int base = tid * 4;
  int r4[4], c4[4], cnt = 0;
  for (int q = 0; q < 4; ++q) {
    r4[q] = rank_ws[b * LL + base + q];
    c4[q] = (r4[q] < lk) ? 1 : 0;
    cnt += c4[q];
  }
  int cur = 0;
  sc[0][tid] = cnt;
  __syncthreads();
  for (int off = 1; off < 1024; off <<= 1) {
    int v = sc[cur][tid];
    if (tid >= off) v += sc[cur][tid - off];
    sc[cur ^ 1][tid] = v;
    __syncthreads();
    cur ^= 1;
  }
  int run = sc[cur][tid] - cnt;  // exclusive prefix

  float4 rst, mmk;
  float* rp = &rst.x; float* mp = &mmk.x;
  for (int q = 0; q < 4; ++q) {
    int j = base + q;
    int r;
    if (c4[q]) {
      r = run;
      keep_idx[b * LL + run] = j;
      out_unmask[(size_t)b * LL + run] = (float)sid[j];
      run++;
    } else {
      r = r4[q];
    }
    rp[q] = (float)r;
    mp[q] = (r >= lk && r < eff) ? 1.0f : 0.0f;
  }
  *reinterpret_cast<float4*>(out_restore + (size_t)b * LL + base) = rst;
  *reinterpret_cast<float4*>(out_mae + (size_t)b * LL + base) = mmk;

  for (int p = tid; p < LL; p += 1024)
    if (p >= lk) out_unmask[(size_t)b * LL + p] = -1.0f;
  if (tid == 0) lk_arr[b] = lk;
}

// ---------------- Kernel D: gather + projection GEMM + epilogue ----------------
// bf16 patch tile in LDS: 20.5 KB -> ~7 blocks/CU (was 41 KB -> 3)
__global__ __launch_bounds__(256) void proj_kernel(
    const float* __restrict__ patches, const float* __restrict__ Wt,
    const float* __restrict__ bias, const float* __restrict__ pos,
    const float* __restrict__ fs_emb, const int* __restrict__ keep_idx,
    const int* __restrict__ lk_arr, float* __restrict__ out0) {
  const int tile = blockIdx.x, b = blockIdx.y, tid = threadIdx.x;
  const int p0 = tile * TP;
  int lk = lk_arr[b];
  lk = lk < 0 ? 0 : (lk > LL ? LL : lk);
  const int h0 = (tid & 63) * 4;
  const int t0 = (tid >> 6) * 4;
  __shared__ __align__(16) unsigned short pT[PDIM * 20];  // [k][t] bf16, stride 20
  __shared__ int idxs[TP];
  int nt = lk - p0;
  nt = nt > TP ? TP : nt;

  if (nt > 0) {
    if (tid < nt) idxs[tid] = keep_idx[b * LL + p0 + tid] & (LL - 1);
    __syncthreads();
    for (int t = 0; t < nt; ++t) {
      const float* row = patches + ((size_t)b * LL + (size_t)idxs[t]) * PDIM;
      pT[tid * 20 + t] = f2bf(row[tid]);
      pT[(tid + 256) * 20 + t] = f2bf(row[tid + 256]);
    }
    __syncthreads();
    float acc[4][4] = {};
    for (int k = 0; k < PDIM; ++k) {
      ushort4 pu = *reinterpret_cast<const ushort4*>(&pT[k * 20 + t0]);  // broadcast in-wave
      float px = bf2f(pu.x), py = bf2f(pu.y), pz_ = bf2f(pu.z), pw = bf2f(pu.w);
      float4 wv = *reinterpret_cast<const float4*>(&Wt[(size_t)k * HH + h0]);
      acc[0][0] += px * wv.x; acc[0][1] += px * wv.y; acc[0][2] += px * wv.z; acc[0][3] += px * wv.w;
      acc[1][0] += py * wv.x; acc[1][1] += py * wv.y; acc[1][2] += py * wv.z; acc[1][3] += py * wv.w;
      acc[2][0] += pz_ * wv.x; acc[2][1] += pz_ * wv.y; acc[2][2] += pz_ * wv.z; acc[2][3] += pz_ * wv.w;
      acc[3][0] += pw * wv.x; acc[3][1] += pw * wv.y; acc[3][2] += pw * wv.z; acc[3][3] += pw * wv.w;
    }
    float4 bv = *reinterpret_cast<const float4*>(&bias[h0]);
    float4 fe = *reinterpret_cast<const float4*>(&fs_emb[b * HH + h0]);
    for (int i = 0; i < 4; ++i) {
      int p = p0 + t0 + i;
      float* op = out0 + ((size_t)b * LL + p) * HH + h0;
      if (p < lk) {
        int idx = idxs[t0 + i];
        float4 pz = *reinterpret_cast<const float4*>(&pos[(size_t)idx * HH + h0]);
        float4 u;
        u.x = acc[i][0] + bv.x + pz.x + fe.x;
        u.y = acc[i][1] + bv.y + pz.y + fe.y;
        u.z = acc[i][2] + bv.z + pz.z + fe.z;
        u.w = acc[i][3] + bv.w + pz.w + fe.w;
        *reinterpret_cast<float4*>(op) = u;
      } else {
        *reinterpret_cast<float4*>(op) = make_float4(0.f, 0.f, 0.f, 0.f);
      }
    }
  } else {
    for (int i = 0; i < 4; ++i) {
      int p = p0 + t0 + i;
      float* op = out0 + ((size_t)b * LL + p) * HH + h0;
      *reinterpret_cast<float4*>(op) = make_float4(0.f, 0.f, 0.f, 0.f);
    }
  }
}

extern "C" void kernel_launch(void* const* d_in, const int* in_sizes, int n_in,
                              void* d_out, int out_size, void* d_ws, size_t ws_size,
                              hipStream_t stream) {
  const float* patches = (const float*)d_in[0];
  const int* sample_ids = (const int*)d_in[1];
  const int* eff = (const int*)d_in[2];
  const float* noise = (const float*)d_in[3];
  const float* fs = (const float*)d_in[4];
  const float* W = (const float*)d_in[5];
  const float* bias = (const float*)d_in[6];
  const float* pos = (const float*)d_in[7];
  const float* w1 = (const float*)d_in[8];
  const float* b1 = (const float*)d_in[9];
  const float* w2 = (const float*)d_in[10];
  const float* b2 = (const float*)d_in[11];

  float* out0 = (float*)d_out;                            // seq_unmasked fp32 [16,4096,256]
  float* out_mae = out0 + (size_t)BB * LL * HH;           // mae_mask   [16,4096]
  float* out_restore = out_mae + (size_t)BB * LL;         // ids_restore[16,4096]
  float* out_unmask = out_restore + (size_t)BB * LL;      // unmask_ids [16,4096]

  char* ws = (char*)d_ws;
  float* Wt = (float*)ws;                        // 524288 B
  float* fs_emb = (float*)(ws + 524288);         // 16384 B
  int* keep_idx = (int*)(ws + 540672);           // 262144 B
  int* rank_ws = (int*)(ws + 802816);            // 262144 B
  int* lk_arr = (int*)(ws + 1064960);            // 64 B
  if (ws_size < 1065024) return;

  wt_kernel<<<512, 256, 0, stream>>>(W, Wt);
  zero_kernel<<<BB * LL / 256, 256, 0, stream>>>(rank_ws);
  fsemb_kernel<<<BB, 256, 0, stream>>>(fs, w1, b1, w2, b2, fs_emb);
  rank_kernel<<<dim3(4, 4, BB), 1024, 0, stream>>>(sample_ids, eff, noise, rank_ws);
  finalize_kernel<<<BB, 1024, 0, stream>>>(sample_ids, eff, rank_ws, out_mae,
                                           out_restore, out_unmask, keep_idx, lk_arr);
  proj_kernel<<<dim3(LL / TP, BB), 256, 0, stream>>>(patches, Wt, bias, pos,
                                                     fs_emb, keep_idx, lk_arr, out0);
}

// Round 5
// 313.107 us; speedup vs baseline: 1.2367x; 1.1455x over previous
//
#include <hip/hip_runtime.h>
#include <hip/hip_bf16.h>

#define BB 16
#define LL 4096
#define PDIM 512
#define HH 256
#define HALFD 128
#define MT 32   // tokens per proj block

typedef short bf16x8 __attribute__((ext_vector_type(8)));   // 8 bf16 in 4 VGPRs
typedef float f32x4 __attribute__((ext_vector_type(4)));

__device__ __forceinline__ unsigned short f2bf(float f) {
  unsigned x = __float_as_uint(f);
  unsigned r = (x + 0x7FFFu + ((x >> 16) & 1u)) >> 16;
  return (unsigned short)r;
}

// stable-sort key for element j of row b: (value_bits << 32) | j  (unique)
__device__ __forceinline__ unsigned long long make_key(
    const int* __restrict__ sid, const float* __restrict__ nrow, int eff, int j) {
  int s = sid[j];
  int sp = (j >= 1) ? sid[j - 1] : -1;
  int spp = (j >= 2) ? sid[j - 2] : -1;
  bool valid = j < eff;
  bool segs = valid && (s != sp);
  bool fst = valid && (j > 0) && (sp != spp);
  unsigned vb;
  if (!valid) vb = 0x7F800000u;            // +inf
  else if (segs || fst) vb = 0u;           // prefix tokens: noise 0
  else vb = __float_as_uint(nrow[j]);      // noise in [0,1): bits monotone
  return (((unsigned long long)vb) << 32) | (unsigned)j;
}

// ---------------- prep: W fp32 [256,512] -> bf16 (same layout) + zero rank_ws ----------------
__global__ __launch_bounds__(256) void prep_kernel(const float* __restrict__ W,
                                                   unsigned short* __restrict__ Wbf,
                                                   int* __restrict__ rank_ws) {
  int idx = blockIdx.x * 256 + threadIdx.x;   // 0..131071
  Wbf[idx] = f2bf(W[idx]);
  if (idx < BB * LL) rank_ws[idx] = 0;
}

// ---------------- fs embedding MLP -> fs_emb [16,256] ----------------
__global__ __launch_bounds__(256) void fsemb_kernel(
    const float* __restrict__ fs, const float* __restrict__ w1,
    const float* __restrict__ b1, const float* __restrict__ w2,
    const float* __restrict__ b2, float* __restrict__ fs_emb) {
  int b = blockIdx.x, h = threadIdx.x;
  __shared__ float tf[HH];
  __shared__ float hid[HH];
  float fv = fs[b];
  int i = h & (HALFD - 1);
  float freq = expf(-9.210340371976184f * (float)i / 128.0f);
  float arg = fv * freq;
  tf[h] = (h < HALFD) ? cosf(arg) : sinf(arg);
  __syncthreads();
  float acc = b1[h];
  const float* wr = w1 + (size_t)h * HH;
  for (int k = 0; k < HH; k += 4) {
    float4 w4 = *reinterpret_cast<const float4*>(&wr[k]);
    acc += tf[k] * w4.x + tf[k + 1] * w4.y + tf[k + 2] * w4.z + tf[k + 3] * w4.w;
  }
  hid[h] = acc / (1.0f + expf(-acc));
  __syncthreads();
  float acc2 = b2[h];
  const float* wr2 = w2 + (size_t)h * HH;
  for (int k = 0; k < HH; k += 4) {
    float4 w4 = *reinterpret_cast<const float4*>(&wr2[k]);
    acc2 += hid[k] * w4.x + hid[k + 1] * w4.y + hid[k + 2] * w4.z + hid[k + 3] * w4.w;
  }
  fs_emb[b * HH + h] = acc2;
}

// ---------------- counting rank (partial, atomic merge) ----------------
__global__ __launch_bounds__(1024) void rank_kernel(
    const int* __restrict__ sample_ids, const int* __restrict__ eff_lens,
    const float* __restrict__ noise, int* __restrict__ rank_ws) {
  const int ks = blockIdx.x, eq = blockIdx.y, b = blockIdx.z, tid = threadIdx.x;
  __shared__ __align__(16) unsigned long long sk[1024];
  const int eff = eff_lens[b];
  const int* sid = sample_ids + (size_t)b * LL;
  const float* nrow = noise + (size_t)b * LL;

  sk[tid] = make_key(sid, nrow, eff, ks * 1024 + tid);
  __syncthreads();

  const int e = eq * 1024 + tid;
  const unsigned long long mykey = make_key(sid, nrow, eff, e);
  int cnt = 0;
#pragma unroll 4
  for (int k = 0; k < 1024; k += 2) {
    ulonglong2 kk = *reinterpret_cast<const ulonglong2*>(&sk[k]);  // broadcast
    cnt += (kk.x < mykey) ? 1 : 0;
    cnt += (kk.y < mykey) ? 1 : 0;
  }
  atomicAdd(&rank_ws[b * LL + e], cnt);
}

// ---------------- finalize: len_keep, kept prefix-scan, index outputs ----------------
__global__ __launch_bounds__(1024) void finalize_kernel(
    const int* __restrict__ sample_ids, const int* __restrict__ eff_lens,
    const int* __restrict__ rank_ws, float* __restrict__ out_mae,
    float* __restrict__ out_restore, float* __restrict__ out_unmask,
    int* __restrict__ keep_idx, int* __restrict__ lk_arr) {
  const int b = blockIdx.x, tid = threadIdx.x;
  __shared__ int sc[2][1024];
  const int eff = eff_lens[b];
  const int* sid = sample_ids + (size_t)b * LL;

  int local_ns = 0;
  for (int j = tid; j < LL; j += 1024) {
    int s = sid[j];
    int sp = (j >= 1) ? sid[j - 1] : -1;
    if (j < eff && s != sp) local_ns++;
  }
  sc[0][tid] = local_ns;
  __syncthreads();
  for (int off = 512; off > 0; off >>= 1) {
    if (tid < off) sc[0][tid] += sc[0][tid + off];
    __syncthreads();
  }
  const int ns = sc[0][0];
  const int lk = 2 * ns + ((eff - 2 * ns) >> 2);  // exact
  __syncthreads();

  const int base = tid * 4;
  int r4[4], c4[4], cnt = 0;
  for (int q = 0; q < 4; ++q) {
    r4[q] = rank_ws[b * LL + base + q];
    c4[q] = (r4[q] < lk) ? 1 : 0;
    cnt += c4[q];
  }
  int cur = 0;
  sc[0][tid] = cnt;
  __syncthreads();
  for (int off = 1; off < 1024; off <<= 1) {
    int v = sc[cur][tid];
    if (tid >= off) v += sc[cur][tid - off];
    sc[cur ^ 1][tid] = v;
    __syncthreads();
    cur ^= 1;
  }
  int run = sc[cur][tid] - cnt;  // exclusive prefix

  float4 rst, mmk;
  float* rp = &rst.x; float* mp = &mmk.x;
  for (int q = 0; q < 4; ++q) {
    int j = base + q;
    int r;
    if (c4[q]) {
      r = run;
      keep_idx[b * LL + run] = j;
      out_unmask[(size_t)b * LL + run] = (float)sid[j];
      run++;
    } else {
      r = r4[q];
    }
    rp[q] = (float)r;
    mp[q] = (r >= lk && r < eff) ? 1.0f : 0.0f;
  }
  *reinterpret_cast<float4*>(out_restore + (size_t)b * LL + base) = rst;
  *reinterpret_cast<float4*>(out_mae + (size_t)b * LL + base) = mmk;

  for (int p = tid; p < LL; p += 1024)
    if (p >= lk) out_unmask[(size_t)b * LL + p] = -1.0f;
  if (tid == 0) lk_arr[b] = lk;
}

// ---------------- proj: MFMA bf16 GEMM, 32 tokens x 256 h x K=512 per block ----------------
__global__ __launch_bounds__(256) void proj_kernel(
    const float* __restrict__ patches, const unsigned short* __restrict__ Wbf,
    const float* __restrict__ bias, const float* __restrict__ pos,
    const float* __restrict__ fs_emb, const int* __restrict__ keep_idx,
    const int* __restrict__ lk_arr, float* __restrict__ out0) {
  const int tile = blockIdx.x, b = blockIdx.y, tid = threadIdx.x;
  const int p0 = tile * MT;
  int lk = lk_arr[b];
  lk = lk < 0 ? 0 : (lk > LL ? LL : lk);
  float* outB = out0 + ((size_t)b * LL + p0) * HH;
  int nt = lk - p0;
  nt = nt > MT ? MT : nt;

  if (nt <= 0) {  // pure zero-fill tile: 32 rows x 1 KB
    float4 z = make_float4(0.f, 0.f, 0.f, 0.f);
    float4* o4 = reinterpret_cast<float4*>(outB);
#pragma unroll
    for (int i = 0; i < MT * HH / 4 / 256; ++i)
      o4[i * 256 + tid] = z;
    return;
  }

  __shared__ __align__(16) unsigned short pA[MT * 520];  // [t][k] bf16, stride 520
  __shared__ int idxs[MT];
  if (tid < MT) idxs[tid] = (tid < nt) ? (keep_idx[b * LL + p0 + tid] & (LL - 1)) : 0;
  __syncthreads();

  {  // stage gathered patch rows as bf16: 8 threads per row, 64 k each
    const int r = tid >> 3, kc = (tid & 7) * 64;
    const float* prow = patches + ((size_t)b * LL + (size_t)idxs[r]) * PDIM + kc;
#pragma unroll
    for (int i = 0; i < 16; ++i) {
      float4 v = reinterpret_cast<const float4*>(prow)[i];
      ushort4 u = make_ushort4(f2bf(v.x), f2bf(v.y), f2bf(v.z), f2bf(v.w));
      *reinterpret_cast<ushort4*>(&pA[r * 520 + kc + i * 4]) = u;
    }
  }
  __syncthreads();

  const int lane = tid & 63, w = tid >> 6;
  const int li = lane & 15, q = lane >> 4;
  f32x4 zero4 = {0.f, 0.f, 0.f, 0.f};
  f32x4 acc[2][4];
#pragma unroll
  for (int m = 0; m < 2; ++m)
#pragma unroll
    for (int n = 0; n < 4; ++n) acc[m][n] = zero4;

#pragma unroll 2
  for (int k0 = 0; k0 < PDIM; k0 += 32) {
    bf16x8 a0 = *reinterpret_cast<const bf16x8*>(&pA[li * 520 + k0 + q * 8]);
    bf16x8 a1 = *reinterpret_cast<const bf16x8*>(&pA[(16 + li) * 520 + k0 + q * 8]);
#pragma unroll
    for (int n = 0; n < 4; ++n) {
      // B[k][col]: col = w*64+n*16+li, k = k0+q*8+j ; Wbf native [h][k] layout
      bf16x8 bf = *reinterpret_cast<const bf16x8*>(
          &Wbf[(size_t)(w * 64 + n * 16 + li) * PDIM + k0 + q * 8]);
      acc[0][n] = __builtin_amdgcn_mfma_f32_16x16x32_bf16(a0, bf, acc[0][n], 0, 0, 0);
      acc[1][n] = __builtin_amdgcn_mfma_f32_16x16x32_bf16(a1, bf, acc[1][n], 0, 0, 0);
    }
  }

  // epilogue: D[row=q*4+r][col=li] (+ bias + pos[idx] + fs_emb), rows >= lk -> 0
#pragma unroll
  for (int m = 0; m < 2; ++m) {
#pragma unroll
    for (int n = 0; n < 4; ++n) {
      const int col = w * 64 + n * 16 + li;
      const float bv = bias[col] + fs_emb[b * HH + col];
#pragma unroll
      for (int rr = 0; rr < 4; ++rr) {
        const int trow = m * 16 + q * 4 + rr;
        float val = 0.f;
        if (p0 + trow < lk)
          val = acc[m][n][rr] + bv + pos[(size_t)idxs[trow] * HH + col];
        outB[(size_t)trow * HH + col] = val;
      }
    }
  }
}

extern "C" void kernel_launch(void* const* d_in, const int* in_sizes, int n_in,
                              void* d_out, int out_size, void* d_ws, size_t ws_size,
                              hipStream_t stream) {
  const float* patches = (const float*)d_in[0];
  const int* sample_ids = (const int*)d_in[1];
  const int* eff = (const int*)d_in[2];
  const float* noise = (const float*)d_in[3];
  const float* fs = (const float*)d_in[4];
  const float* W = (const float*)d_in[5];
  const float* bias = (const float*)d_in[6];
  const float* pos = (const float*)d_in[7];
  const float* w1 = (const float*)d_in[8];
  const float* b1 = (const float*)d_in[9];
  const float* w2 = (const float*)d_in[10];
  const float* b2 = (const float*)d_in[11];

  float* out0 = (float*)d_out;                            // seq_unmasked fp32 [16,4096,256]
  float* out_mae = out0 + (size_t)BB * LL * HH;           // mae_mask   [16,4096]
  float* out_restore = out_mae + (size_t)BB * LL;         // ids_restore[16,4096]
  float* out_unmask = out_restore + (size_t)BB * LL;      // unmask_ids [16,4096]

  char* ws = (char*)d_ws;
  unsigned short* Wbf = (unsigned short*)ws;     // 262144 B (bf16 [256][512])
  float* fs_emb = (float*)(ws + 262144);         // 16384 B
  int* keep_idx = (int*)(ws + 278528);           // 262144 B
  int* rank_ws = (int*)(ws + 540672);            // 262144 B
  int* lk_arr = (int*)(ws + 802816);             // 64 B
  if (ws_size < 802880) return;

  prep_kernel<<<512, 256, 0, stream>>>(W, Wbf, rank_ws);
  fsemb_kernel<<<BB, 256, 0, stream>>>(fs, w1, b1, w2, b2, fs_emb);
  rank_kernel<<<dim3(4, 4, BB), 1024, 0, stream>>>(sample_ids, eff, noise, rank_ws);
  finalize_kernel<<<BB, 1024, 0, stream>>>(sample_ids, eff, rank_ws, out_mae,
                                           out_restore, out_unmask, keep_idx, lk_arr);
  proj_kernel<<<dim3(LL / MT, BB), 256, 0, stream>>>(patches, Wbf, bias, pos,
                                                     fs_emb, keep_idx, lk_arr, out0);
}

// Round 6
// 311.438 us; speedup vs baseline: 1.2433x; 1.0054x over previous
//
#include <hip/hip_runtime.h>
#include <hip/hip_bf16.h>

#define BB 16
#define LL 4096
#define PDIM 512
#define HH 256
#define HALFD 128
#define MT 32   // tokens per proj block

typedef short bf16x8 __attribute__((ext_vector_type(8)));   // 8 bf16 in 4 VGPRs
typedef float f32x4 __attribute__((ext_vector_type(4)));

__device__ __forceinline__ unsigned short f2bf(float f) {
  unsigned x = __float_as_uint(f);
  unsigned r = (x + 0x7FFFu + ((x >> 16) & 1u)) >> 16;
  return (unsigned short)r;
}

// stable-sort key for element j of row b: (value_bits << 32) | j  (unique)
__device__ __forceinline__ unsigned long long make_key(
    const int* __restrict__ sid, const float* __restrict__ nrow, int eff, int j) {
  int s = sid[j];
  int sp = (j >= 1) ? sid[j - 1] : -1;
  int spp = (j >= 2) ? sid[j - 2] : -1;
  bool valid = j < eff;
  bool segs = valid && (s != sp);
  bool fst = valid && (j > 0) && (sp != spp);
  unsigned vb;
  if (!valid) vb = 0x7F800000u;            // +inf
  else if (segs || fst) vb = 0u;           // prefix tokens: noise 0
  else vb = __float_as_uint(nrow[j]);      // noise in [0,1): bits monotone
  return (((unsigned long long)vb) << 32) | (unsigned)j;
}

// ---------------- prep: W->bf16 (blocks 0..511)  +  fs MLP (blocks 512..527) ----------------
__global__ __launch_bounds__(256) void prep_kernel(
    const float* __restrict__ W, unsigned short* __restrict__ Wbf,
    const float* __restrict__ fs, const float* __restrict__ w1,
    const float* __restrict__ b1, const float* __restrict__ w2,
    const float* __restrict__ b2, float* __restrict__ fs_emb) {
  __shared__ float tf[HH];
  __shared__ float hid[HH];
  if (blockIdx.x < 512) {
    int idx = blockIdx.x * 256 + threadIdx.x;   // 0..131071
    Wbf[idx] = f2bf(W[idx]);
    return;
  }
  const int b = blockIdx.x - 512, h = threadIdx.x;
  float fv = fs[b];
  int i = h & (HALFD - 1);
  float freq = expf(-9.210340371976184f * (float)i / 128.0f);
  float arg = fv * freq;
  tf[h] = (h < HALFD) ? cosf(arg) : sinf(arg);
  __syncthreads();
  float acc = b1[h];
  const float* wr = w1 + (size_t)h * HH;
  for (int k = 0; k < HH; k += 4) {
    float4 w4 = *reinterpret_cast<const float4*>(&wr[k]);
    acc += tf[k] * w4.x + tf[k + 1] * w4.y + tf[k + 2] * w4.z + tf[k + 3] * w4.w;
  }
  hid[h] = acc / (1.0f + expf(-acc));
  __syncthreads();
  float acc2 = b2[h];
  const float* wr2 = w2 + (size_t)h * HH;
  for (int k = 0; k < HH; k += 4) {
    float4 w4 = *reinterpret_cast<const float4*>(&wr2[k]);
    acc2 += hid[k] * w4.x + hid[k + 1] * w4.y + hid[k + 2] * w4.z + hid[k + 3] * w4.w;
  }
  fs_emb[b * HH + h] = acc2;
}

// ---------------- counting rank: partials, no atomics ----------------
// grid (4 own-quarters, 4 other-slices, 16 rows) x 512 thr; 2 own keys/thread.
// rank_part[os][b][e] = #{keys in slice os < key[e]}
__global__ __launch_bounds__(512) void rank_kernel(
    const int* __restrict__ sample_ids, const int* __restrict__ eff_lens,
    const float* __restrict__ noise, int* __restrict__ rank_part) {
  const int oq = blockIdx.x, os = blockIdx.y, b = blockIdx.z, tid = threadIdx.x;
  __shared__ __align__(16) unsigned long long sk[1024];
  const int eff = eff_lens[b];
  const int* sid = sample_ids + (size_t)b * LL;
  const float* nrow = noise + (size_t)b * LL;

  sk[tid] = make_key(sid, nrow, eff, os * 1024 + tid);
  sk[tid + 512] = make_key(sid, nrow, eff, os * 1024 + tid + 512);
  const int e0 = oq * 1024 + tid * 2;
  const unsigned long long k0 = make_key(sid, nrow, eff, e0);
  const unsigned long long k1 = make_key(sid, nrow, eff, e0 + 1);
  __syncthreads();

  int c0 = 0, c1 = 0;
#pragma unroll 8
  for (int k = 0; k < 1024; k += 2) {
    ulonglong2 kk = *reinterpret_cast<const ulonglong2*>(&sk[k]);  // wave broadcast
    c0 += (kk.x < k0) ? 1 : 0;
    c0 += (kk.y < k0) ? 1 : 0;
    c1 += (kk.x < k1) ? 1 : 0;
    c1 += (kk.y < k1) ? 1 : 0;
  }
  int2 res = make_int2(c0, c1);
  *reinterpret_cast<int2*>(&rank_part[((size_t)os * BB + b) * LL + e0]) = res;
}

// ---------------- finalize: len_keep, kept prefix-scan (shfl), index outputs ----------------
__global__ __launch_bounds__(1024) void finalize_kernel(
    const int* __restrict__ sample_ids, const int* __restrict__ eff_lens,
    const int* __restrict__ rank_part, float* __restrict__ out_mae,
    float* __restrict__ out_restore, float* __restrict__ out_unmask,
    int* __restrict__ keep_idx, int* __restrict__ lk_arr) {
  const int b = blockIdx.x, tid = threadIdx.x;
  const int wid = tid >> 6, lane = tid & 63;
  __shared__ int wsum[16];
  __shared__ int lksh;
  const int eff = eff_lens[b];
  const int* sid = sample_ids + (size_t)b * LL;

  // ---- ns = # segment starts ----
  int local_ns = 0;
  for (int j = tid; j < LL; j += 1024) {
    int s = sid[j];
    int sp = (j >= 1) ? sid[j - 1] : -1;
    if (j < eff && s != sp) local_ns++;
  }
#pragma unroll
  for (int off = 32; off > 0; off >>= 1) local_ns += __shfl_down(local_ns, off);
  if (lane == 0) wsum[wid] = local_ns;
  __syncthreads();
  if (wid == 0) {
    int v = (lane < 16) ? wsum[lane] : 0;
#pragma unroll
    for (int off = 32; off > 0; off >>= 1) v += __shfl_down(v, off);
    if (lane == 0) {
      int ns = v;
      lksh = 2 * ns + ((eff - 2 * ns) >> 2);  // exact
    }
  }
  __syncthreads();
  const int lk = lksh;

  // ---- kept flags (sum rank partials) + exclusive prefix via shfl scan ----
  const int base = tid * 4;
  int4 p0 = *reinterpret_cast<const int4*>(&rank_part[((size_t)0 * BB + b) * LL + base]);
  int4 p1 = *reinterpret_cast<const int4*>(&rank_part[((size_t)1 * BB + b) * LL + base]);
  int4 p2 = *reinterpret_cast<const int4*>(&rank_part[((size_t)2 * BB + b) * LL + base]);
  int4 p3 = *reinterpret_cast<const int4*>(&rank_part[((size_t)3 * BB + b) * LL + base]);
  int r4[4] = {p0.x + p1.x + p2.x + p3.x, p0.y + p1.y + p2.y + p3.y,
               p0.z + p1.z + p2.z + p3.z, p0.w + p1.w + p2.w + p3.w};
  int c4[4], cnt = 0;
#pragma unroll
  for (int q = 0; q < 4; ++q) { c4[q] = (r4[q] < lk) ? 1 : 0; cnt += c4[q]; }

  int incl = cnt;
#pragma unroll
  for (int off = 1; off < 64; off <<= 1) {
    int v = __shfl_up(incl, off);
    if (lane >= off) incl += v;
  }
  if (lane == 63) wsum[wid] = incl;
  __syncthreads();
  if (wid == 0) {
    int s = (lane < 16) ? wsum[lane] : 0;
#pragma unroll
    for (int off = 1; off < 16; off <<= 1) {
      int v = __shfl_up(s, off);
      if (lane >= off) s += v;
    }
    if (lane < 16) wsum[lane] = s;  // inclusive wave sums
  }
  __syncthreads();
  int run = ((wid > 0) ? wsum[wid - 1] : 0) + incl - cnt;  // exclusive prefix

  float4 rst, mmk;
  float* rp = &rst.x; float* mp = &mmk.x;
#pragma unroll
  for (int q = 0; q < 4; ++q) {
    int j = base + q;
    int r;
    if (c4[q]) {
      r = run;
      keep_idx[b * LL + run] = j;
      out_unmask[(size_t)b * LL + run] = (float)sid[j];
      run++;
    } else {
      r = r4[q];
    }
    rp[q] = (float)r;
    mp[q] = (r >= lk && r < eff) ? 1.0f : 0.0f;
  }
  *reinterpret_cast<float4*>(out_restore + (size_t)b * LL + base) = rst;
  *reinterpret_cast<float4*>(out_mae + (size_t)b * LL + base) = mmk;

  for (int p = tid; p < LL; p += 1024)
    if (p >= lk) out_unmask[(size_t)b * LL + p] = -1.0f;
  if (tid == 0) lk_arr[b] = lk;
}

// ---------------- proj: MFMA bf16 GEMM, 32 tokens x 256 h x K=512 per block ----------------
__global__ __launch_bounds__(256) void proj_kernel(
    const float* __restrict__ patches, const unsigned short* __restrict__ Wbf,
    const float* __restrict__ bias, const float* __restrict__ pos,
    const float* __restrict__ fs_emb, const int* __restrict__ keep_idx,
    const int* __restrict__ lk_arr, float* __restrict__ out0) {
  const int tile = blockIdx.x, b = blockIdx.y, tid = threadIdx.x;
  const int p0 = tile * MT;
  int lk = lk_arr[b];
  lk = lk < 0 ? 0 : (lk > LL ? LL : lk);
  float* outB = out0 + ((size_t)b * LL + p0) * HH;
  int nt = lk - p0;
  nt = nt > MT ? MT : nt;

  if (nt <= 0) {  // pure zero-fill tile
    float4 z = make_float4(0.f, 0.f, 0.f, 0.f);
    float4* o4 = reinterpret_cast<float4*>(outB);
#pragma unroll
    for (int i = 0; i < MT * HH / 4 / 256; ++i)
      o4[i * 256 + tid] = z;
    return;
  }

  __shared__ __align__(16) unsigned short pA[MT * 520];  // [t][k] bf16, stride 520
  __shared__ int idxs[MT];
  if (tid < MT) idxs[tid] = (tid < nt) ? (keep_idx[b * LL + p0 + tid] & (LL - 1)) : 0;
  __syncthreads();

  {  // stage gathered patch rows as bf16: 8 threads per row, 64 k each
    const int r = tid >> 3, kc = (tid & 7) * 64;
    const float* prow = patches + ((size_t)b * LL + (size_t)idxs[r]) * PDIM + kc;
#pragma unroll
    for (int i = 0; i < 16; ++i) {
      float4 v = reinterpret_cast<const float4*>(prow)[i];
      ushort4 u = make_ushort4(f2bf(v.x), f2bf(v.y), f2bf(v.z), f2bf(v.w));
      *reinterpret_cast<ushort4*>(&pA[r * 520 + kc + i * 4]) = u;
    }
  }
  __syncthreads();

  const int lane = tid & 63, w = tid >> 6;
  const int li = lane & 15, q = lane >> 4;
  f32x4 zero4 = {0.f, 0.f, 0.f, 0.f};
  f32x4 acc[2][4];
#pragma unroll
  for (int m = 0; m < 2; ++m)
#pragma unroll
    for (int n = 0; n < 4; ++n) acc[m][n] = zero4;

#pragma unroll 2
  for (int k0 = 0; k0 < PDIM; k0 += 32) {
    bf16x8 a0 = *reinterpret_cast<const bf16x8*>(&pA[li * 520 + k0 + q * 8]);
    bf16x8 a1 = *reinterpret_cast<const bf16x8*>(&pA[(16 + li) * 520 + k0 + q * 8]);
#pragma unroll
    for (int n = 0; n < 4; ++n) {
      bf16x8 bf = *reinterpret_cast<const bf16x8*>(
          &Wbf[(size_t)(w * 64 + n * 16 + li) * PDIM + k0 + q * 8]);
      acc[0][n] = __builtin_amdgcn_mfma_f32_16x16x32_bf16(a0, bf, acc[0][n], 0, 0, 0);
      acc[1][n] = __builtin_amdgcn_mfma_f32_16x16x32_bf16(a1, bf, acc[1][n], 0, 0, 0);
    }
  }

  // epilogue: D[row=q*4+r][col=li] (+ bias + pos[idx] + fs_emb), rows >= lk -> 0
#pragma unroll
  for (int m = 0; m < 2; ++m) {
#pragma unroll
    for (int n = 0; n < 4; ++n) {
      const int col = w * 64 + n * 16 + li;
      const float bv = bias[col] + fs_emb[b * HH + col];
#pragma unroll
      for (int rr = 0; rr < 4; ++rr) {
        const int trow = m * 16 + q * 4 + rr;
        float val = 0.f;
        if (p0 + trow < lk)
          val = acc[m][n][rr] + bv + pos[(size_t)idxs[trow] * HH + col];
        outB[(size_t)trow * HH + col] = val;
      }
    }
  }
}

extern "C" void kernel_launch(void* const* d_in, const int* in_sizes, int n_in,
                              void* d_out, int out_size, void* d_ws, size_t ws_size,
                              hipStream_t stream) {
  const float* patches = (const float*)d_in[0];
  const int* sample_ids = (const int*)d_in[1];
  const int* eff = (const int*)d_in[2];
  const float* noise = (const float*)d_in[3];
  const float* fs = (const float*)d_in[4];
  const float* W = (const float*)d_in[5];
  const float* bias = (const float*)d_in[6];
  const float* pos = (const float*)d_in[7];
  const float* w1 = (const float*)d_in[8];
  const float* b1 = (const float*)d_in[9];
  const float* w2 = (const float*)d_in[10];
  const float* b2 = (const float*)d_in[11];

  float* out0 = (float*)d_out;                            // seq_unmasked fp32 [16,4096,256]
  float* out_mae = out0 + (size_t)BB * LL * HH;           // mae_mask   [16,4096]
  float* out_restore = out_mae + (size_t)BB * LL;         // ids_restore[16,4096]
  float* out_unmask = out_restore + (size_t)BB * LL;      // unmask_ids [16,4096]

  char* ws = (char*)d_ws;
  unsigned short* Wbf = (unsigned short*)ws;     // 262144 B (bf16 [256][512])
  float* fs_emb = (float*)(ws + 262144);         // 16384 B
  int* keep_idx = (int*)(ws + 278528);           // 262144 B
  int* rank_part = (int*)(ws + 540672);          // 4*16*4096*4 = 1048576 B
  int* lk_arr = (int*)(ws + 1589248);            // 64 B
  if (ws_size < 1589312) return;

  prep_kernel<<<528, 256, 0, stream>>>(W, Wbf, fs, w1, b1, w2, b2, fs_emb);
  rank_kernel<<<dim3(4, 4, BB), 512, 0, stream>>>(sample_ids, eff, noise, rank_part);
  finalize_kernel<<<BB, 1024, 0, stream>>>(sample_ids, eff, rank_part, out_mae,
                                           out_restore, out_unmask, keep_idx, lk_arr);
  proj_kernel<<<dim3(LL / MT, BB), 256, 0, stream>>>(patches, Wbf, bias, pos,
                                                     fs_emb, keep_idx, lk_arr, out0);
}